// Round 4
// baseline (281.975 us; speedup 1.0000x reference)
//
#include <hip/hip_runtime.h>
#include <hip/hip_bf16.h>
#include <stdint.h>

#define B_    2
#define S_    4096
#define D_    768
#define H_    12
#define DH_   64
#define BH_   (B_*H_)
#define M_    (B_*S_)       // 8192
#define NQKV_ 2304
// 1/sqrt(64) * log2(e): Q pre-scaled so softmax runs in exp2 space
#define QSCALE_ 0.18033688011112042f

typedef unsigned short bf16u;
typedef short bf16x8 __attribute__((ext_vector_type(8)));
typedef float f32x4 __attribute__((ext_vector_type(4)));

__device__ __forceinline__ bf16u f2bf(float f) {
    unsigned u = __float_as_uint(f);
    u += 0x7FFFu + ((u >> 16) & 1u);   // round-to-nearest-even
    return (bf16u)(u >> 16);
}

__device__ __forceinline__ void gl_lds16(const void* g, void* l) {
    __builtin_amdgcn_global_load_lds(
        (const __attribute__((address_space(1))) unsigned*)g,
        (__attribute__((address_space(3))) unsigned*)l, 16, 0, 0);
}

// ---------------------------------------------------------------- convert
// R4: three tensors in one launch (boundaries are multiples of 256 quads,
// so no intra-block divergence); saves 2 kernel-launch gaps.
#define N1Q_ 1572864   // x      quads
#define N2Q_  442368   // W_qkv  quads
#define N3Q_  147456   // W_out  quads
__global__ __launch_bounds__(256) void convert3_kernel(
    const float* __restrict__ s1, const float* __restrict__ s2,
    const float* __restrict__ s3, bf16u* __restrict__ d1,
    bf16u* __restrict__ d2, bf16u* __restrict__ d3)
{
    int i = blockIdx.x * 256 + threadIdx.x;
    const float* s; bf16u* d; int j;
    if (i < N1Q_)              { s = s1; d = d1; j = i; }
    else if (i < N1Q_ + N2Q_)  { s = s2; d = d2; j = i - N1Q_; }
    else                       { s = s3; d = d3; j = i - N1Q_ - N2Q_; }
    float4 v = ((const float4*)s)[j];
    ushort4 o;
    o.x = f2bf(v.x); o.y = f2bf(v.y); o.z = f2bf(v.z); o.w = f2bf(v.w);
    ((ushort4*)d)[j] = o;
}

// ---------------------------------------------------------------- GEMM
// C[m][n] = sum_k A[m][k]*Bw[n][k] + bias[n].  K = 768 for both GEMMs.
// LDS rows are 4 chunks of 16B; chunk-slot XOR-swizzled by (row&3).
// XCD-bijective block swizzle (T1) — grids are 1152 / 384, both %8==0.
// EPI==0: fp32 store to Cout.  EPI==1: scatter to Qb(scaled)/Kb(bh,s,dh)/Vtb(bh,dh,s).
template<int EPI>
__global__ __launch_bounds__(256) void gemm_kernel(
    const bf16u* __restrict__ A, const bf16u* __restrict__ Bw,
    const float* __restrict__ bias, float* __restrict__ Cout,
    bf16u* __restrict__ Qb, bf16u* __restrict__ Kb, bf16u* __restrict__ Vtb)
{
    __shared__ bf16u As[128*32];
    __shared__ bf16u Bs[128*32];
    const int tid  = threadIdx.x;
    const int lane = tid & 63;
    const int wave = tid >> 6;
    const int wr = wave >> 1, wc = wave & 1;
    const int lr = lane & 15;
    const int quad = lane >> 4;

    const int nwg  = gridDim.x * gridDim.y;
    const int fblk = blockIdx.y * gridDim.x + blockIdx.x;
    const int vblk = (fblk & 7) * (nwg >> 3) + (fblk >> 3);
    const int m0 = (vblk / gridDim.x) * 128;
    const int n0 = (vblk % gridDim.x) * 128;

    f32x4 acc[4][4];
    #pragma unroll
    for (int i = 0; i < 4; i++)
        #pragma unroll
        for (int j = 0; j < 4; j++)
            acc[i][j] = (f32x4){0.f, 0.f, 0.f, 0.f};

    for (int k0 = 0; k0 < 768; k0 += 32) {
        #pragma unroll
        for (int r = 0; r < 2; r++) {
            int c = r * 256 + tid;              // 0..511 chunks of 16B
            int row = c >> 2;                   // 4 chunks per 64B row
            int col = ((c & 3) ^ (row & 3)) * 8; // XOR-swizzled source chunk
            gl_lds16(A  + (size_t)(m0 + row) * 768 + k0 + col, (char*)As + c * 16);
            gl_lds16(Bw + (size_t)(n0 + row) * 768 + k0 + col, (char*)Bs + c * 16);
        }
        __syncthreads();
        bf16x8 af[4], bg[4];
        #pragma unroll
        for (int t = 0; t < 4; t++) {
            int ra = wr * 64 + t * 16 + lr;
            int rb = wc * 64 + t * 16 + lr;
            af[t] = *(const bf16x8*)(As + ra * 32 + ((quad ^ (ra & 3)) * 8));
            bg[t] = *(const bf16x8*)(Bs + rb * 32 + ((quad ^ (rb & 3)) * 8));
        }
        #pragma unroll
        for (int i = 0; i < 4; i++)
            #pragma unroll
            for (int j = 0; j < 4; j++)
                acc[i][j] = __builtin_amdgcn_mfma_f32_16x16x32_bf16(
                    af[i], bg[j], acc[i][j], 0, 0, 0);
        __syncthreads();
    }

    #pragma unroll
    for (int i = 0; i < 4; i++) {
        int mbase = m0 + wr * 64 + i * 16 + quad * 4;
        #pragma unroll
        for (int j = 0; j < 4; j++) {
            int n = n0 + wc * 64 + j * 16 + lr;
            float bv = bias[n];
            if (EPI == 0) {
                #pragma unroll
                for (int r = 0; r < 4; r++)
                    Cout[(size_t)(mbase + r) * 768 + n] = acc[i][j][r] + bv;
            } else {
                int t3  = n / 768;
                int rem = n - t3 * 768;
                int h   = rem >> 6;
                int dh  = rem & 63;
                #pragma unroll
                for (int r = 0; r < 4; r++) {
                    int mm = mbase + r;
                    int b  = mm >> 12;      // /4096
                    int s  = mm & 4095;
                    int bh = b * H_ + h;
                    float v = acc[i][j][r] + bv;
                    if (t3 == 0)
                        Qb[((size_t)bh * S_ + s) * DH_ + dh] = f2bf(v * QSCALE_);
                    else if (t3 == 1)
                        Kb[((size_t)bh * S_ + s) * DH_ + dh] = f2bf(v);
                    else
                        Vtb[((size_t)bh * DH_ + dh) * S_ + s] = f2bf(v);
                }
            }
        }
    }
}

// ---------------------------------------------------------------- attention
// R4 restructure (LDS-read-pipe fix):
//  * R3 was MfmaUtil 48 / VALUBusy 55 / conflicts 0 / HBM 3.6% — neither
//    issue pipe saturated; limiter is the LDS read pipe. Each wave read the
//    FULL 8KB K + 8KB V tile (16 ds_read_b128/iter) for only 16 q-rows; K/V
//    reads don't scale with q-rows, so 8 waves re-read the same data 8x.
//  * Now 4 waves x 256 threads, each wave owns 32 q-rows (rh=0,1 halves):
//    same 16 b128/iter per wave but 2x the MFMA work -> LDS:MFMA ~1:1.
//    Grid stays 768 blocks = exactly 3/CU; 12 waves/CU.
//  * P stays in-register (T12 permlane network, R3-verified).
//  * __launch_bounds__(256,4) caps VGPR at 128 (est. ~110) so 3 blocks fit.
__global__ __launch_bounds__(256, 4) void attn_kernel(
    const bf16u* __restrict__ Qb, const bf16u* __restrict__ Kb,
    const bf16u* __restrict__ Vtb, bf16u* __restrict__ A2)
{
    __shared__ char Lds[32768];   // [K buf0 | K buf1 | V buf0 | V buf1], 8KB each
    const int tid  = threadIdx.x;
    const int lane = tid & 63;
    const int w    = tid >> 6;          // 0..3
    const int lr   = lane & 15;
    const int quad = lane >> 4;

    // XCD-bijective swizzle: 768 blocks, 96 per XCD (= 3 full bh panels)
    const int fblk = blockIdx.y * gridDim.x + blockIdx.x;
    const int vblk = (fblk & 7) * 96 + (fblk >> 3);
    const int q0   = (vblk & 31) * 128;
    const int bh   = vblk >> 5;

    const size_t kbase_g = (size_t)bh * S_ * DH_;
    const size_t vbase_g = (size_t)bh * DH_ * S_;

    // Q B-fragments: aq[rh][ks], qrows q0+32w+16rh+lr, feats ks*32+quad*8
    bf16x8 aq[2][2];
    #pragma unroll
    for (int rh = 0; rh < 2; rh++) {
        const size_t qb = ((size_t)bh * S_ + q0 + w * 32 + rh * 16 + lr) * DH_ + quad * 8;
        aq[rh][0] = *(const bf16x8*)(Qb + qb);
        aq[rh][1] = *(const bf16x8*)(Qb + qb + 32);
    }

    bf16x8 onesf;
    #pragma unroll
    for (int j = 0; j < 8; j++) onesf[j] = (short)0x3F80;  // bf16 1.0

    f32x4 o[2][4];       // C-layout: [qrow=quad*4+r2][dh=nt*16+lr]
    f32x4 l_acc[2];
    #pragma unroll
    for (int rh = 0; rh < 2; rh++) {
        l_acc[rh] = (f32x4){0.f, 0.f, 0.f, 0.f};
        #pragma unroll
        for (int t = 0; t < 4; t++) o[rh][t] = (f32x4){0.f, 0.f, 0.f, 0.f};
    }

    // Hoisted K/V LDS byte offsets (same swizzled geometry for K and V tiles)
    int kvaddr[4][2];
    #pragma unroll
    for (int nt = 0; nt < 4; nt++) {
        int rk = nt * 16 + lr;
        kvaddr[nt][0] = (rk * 64 + ((quad ^ (rk & 7)) * 8)) * 2;
        kvaddr[nt][1] = (rk * 64 + (((4 + quad) ^ (rk & 7)) * 8)) * 2;
    }

    // stage KV tile kv0 into buffer bf (256 threads -> 2 chunks each per matrix)
    auto stage = [&](int kv0, int bf) {
        #pragma unroll
        for (int r = 0; r < 2; r++) {
            int c = r * 256 + tid;                  // 0..511 chunks of 16B
            int row = c >> 3;
            int col = ((c & 7) ^ (row & 7)) * 8;    // XOR-swizzled source chunk
            gl_lds16(Kb  + kbase_g + (size_t)(kv0 + row) * DH_ + col,
                     Lds + bf * 8192 + c * 16);
            gl_lds16(Vtb + vbase_g + (size_t)row * S_ + kv0 + col,
                     Lds + 16384 + bf * 8192 + c * 16);
        }
    };

    stage(0, 0);

    // one KV-tile step; buf/do_stage are compile-time constants per call site
    auto body = [&](int it, int buf, bool do_stage) __attribute__((always_inline)) {
        __syncthreads();                       // tile `it` staged; prev compute done
        if (do_stage) stage((it + 1) * 64, buf ^ 1);

        const char* Kbuf = Lds + buf * 8192;
        const char* Vbuf = Lds + 16384 + buf * 8192;

        // S^T = K @ Q^T  (exp2-scaled).  C[m=key_local][n=qrow_local]
        // K frags read ONCE per nt, used by both rh halves.
        f32x4 sc[2][4];
        __builtin_amdgcn_s_setprio(1);
        #pragma unroll
        for (int nt = 0; nt < 4; nt++) {
            const bf16x8 bk0 = *(const bf16x8*)(Kbuf + kvaddr[nt][0]);
            const bf16x8 bk1 = *(const bf16x8*)(Kbuf + kvaddr[nt][1]);
            #pragma unroll
            for (int rh = 0; rh < 2; rh++) {
                f32x4 s = (f32x4){0.f, 0.f, 0.f, 0.f};
                s = __builtin_amdgcn_mfma_f32_16x16x32_bf16(bk0, aq[rh][0], s, 0, 0, 0);
                s = __builtin_amdgcn_mfma_f32_16x16x32_bf16(bk1, aq[rh][1], s, 0, 0, 0);
                sc[rh][nt] = s;
            }
        }
        __builtin_amdgcn_s_setprio(0);

        // P = exp2(S): pack to bf16 pairs, all in-register
        unsigned W[2][4][2];
        #pragma unroll
        for (int rh = 0; rh < 2; rh++) {
            #pragma unroll
            for (int nt = 0; nt < 4; nt++) {
                float p0 = __builtin_amdgcn_exp2f(sc[rh][nt][0]);
                float p1 = __builtin_amdgcn_exp2f(sc[rh][nt][1]);
                float p2 = __builtin_amdgcn_exp2f(sc[rh][nt][2]);
                float p3 = __builtin_amdgcn_exp2f(sc[rh][nt][3]);
                // pack high-16s (truncation; bias cancels in o/l ratio)
                W[rh][nt][0] = __builtin_amdgcn_perm(__float_as_uint(p1),
                                                     __float_as_uint(p0), 0x07060302u);
                W[rh][nt][1] = __builtin_amdgcn_perm(__float_as_uint(p3),
                                                     __float_as_uint(p2), 0x07060302u);
            }
        }

        // permlane network: (W[rh][2ks][b], W[rh][2ks+1][b]) -> (a[b], a[2+b])
        bf16x8 ap[2][2];
        #pragma unroll
        for (int rh = 0; rh < 2; rh++) {
            #pragma unroll
            for (int ks = 0; ks < 2; ks++) {
                union { unsigned u[4]; bf16x8 v; } Af;
                #pragma unroll
                for (int b = 0; b < 2; b++) {
                    auto r1 = __builtin_amdgcn_permlane32_swap(
                        W[rh][2 * ks][b], W[rh][2 * ks + 1][b], false, false);
                    auto r2 = __builtin_amdgcn_permlane16_swap(
                        r1[0], r1[1], false, false);
                    Af.u[b]     = r2[0];
                    Af.u[2 + b] = r2[1];
                }
                ap[rh][ks] = Af.v;
            }
        }

        // O += P @ V ; l += P @ 1.  V frags read ONCE per nt, both rh use them.
        __builtin_amdgcn_s_setprio(1);
        #pragma unroll
        for (int rh = 0; rh < 2; rh++) {
            l_acc[rh] = __builtin_amdgcn_mfma_f32_16x16x32_bf16(ap[rh][0], onesf, l_acc[rh], 0, 0, 0);
            l_acc[rh] = __builtin_amdgcn_mfma_f32_16x16x32_bf16(ap[rh][1], onesf, l_acc[rh], 0, 0, 0);
        }
        #pragma unroll
        for (int nt = 0; nt < 4; nt++) {
            const bf16x8 bv0 = *(const bf16x8*)(Vbuf + kvaddr[nt][0]);
            const bf16x8 bv1 = *(const bf16x8*)(Vbuf + kvaddr[nt][1]);
            #pragma unroll
            for (int rh = 0; rh < 2; rh++) {
                o[rh][nt] = __builtin_amdgcn_mfma_f32_16x16x32_bf16(ap[rh][0], bv0, o[rh][nt], 0, 0, 0);
                o[rh][nt] = __builtin_amdgcn_mfma_f32_16x16x32_bf16(ap[rh][1], bv1, o[rh][nt], 0, 0, 0);
            }
        }
        __builtin_amdgcn_s_setprio(0);
    };

    // unroll x2 so buf is a literal in each copy; explicit 2-tile tail
    #pragma unroll 1
    for (int it = 0; it < S_ / 64 - 2; it += 2) {
        body(it,     0, true);
        body(it + 1, 1, true);
    }
    body(S_ / 64 - 2, 0, true);
    body(S_ / 64 - 1, 1, false);

    const int b = bh / H_, h = bh % H_;
    #pragma unroll
    for (int rh = 0; rh < 2; rh++) {
        float rl[4];
        #pragma unroll
        for (int r2 = 0; r2 < 4; r2++) rl[r2] = 1.0f / l_acc[rh][r2];
        #pragma unroll
        for (int nt = 0; nt < 4; nt++)
            #pragma unroll
            for (int r2 = 0; r2 < 4; r2++) {
                int q = q0 + w * 32 + rh * 16 + quad * 4 + r2;
                float v = o[rh][nt][r2] * rl[r2];
                A2[((size_t)b * S_ + q) * D_ + h * DH_ + nt * 16 + lr] = f2bf(v);
            }
    }
}

// ---------------------------------------------------------------- launch
extern "C" void kernel_launch(void* const* d_in, const int* in_sizes, int n_in,
                              void* d_out, int out_size, void* d_ws, size_t ws_size,
                              hipStream_t stream) {
    const float* x     = (const float*)d_in[0];
    const float* W_qkv = (const float*)d_in[1];
    const float* b_qkv = (const float*)d_in[2];
    const float* W_out = (const float*)d_in[3];
    const float* b_out = (const float*)d_in[4];
    float* out = (float*)d_out;
    char* ws = (char*)d_ws;

    // workspace layout (bytes, all 256-aligned)
    bf16u* xb    = (bf16u*)(ws + 0);          // 8192*768*2  = 12582912
    bf16u* wqkvb = (bf16u*)(ws + 12582912);   // 2304*768*2  =  3538944
    bf16u* woutb = (bf16u*)(ws + 16121856);   //  768*768*2  =  1179648
    bf16u* Qb    = (bf16u*)(ws + 17301504);   // 24*4096*64*2 = 12582912
    bf16u* Kb    = (bf16u*)(ws + 29884416);
    bf16u* Vtb   = (bf16u*)(ws + 42467328);
    bf16u* A2    = (bf16u*)(ws + 55050240);   // 8192*768*2

    convert3_kernel<<<(N1Q_ + N2Q_ + N3Q_) / 256, 256, 0, stream>>>(
        x, W_qkv, W_out, xb, wqkvb, woutb);

    dim3 g1(NQKV_/128, M_/128);   // 18 x 64 = 1152 blocks (%8==0)
    gemm_kernel<1><<<g1, 256, 0, stream>>>(xb, wqkvb, b_qkv, nullptr, Qb, Kb, Vtb);

    dim3 g2(S_/128, BH_);         // 32 x 24 = 768 blocks, 256 thr, 3/CU
    attn_kernel<<<g2, 256, 0, stream>>>(Qb, Kb, Vtb, A2);

    dim3 g3(D_/128, M_/128);      // 6 x 64 = 384 blocks (%8==0)
    gemm_kernel<0><<<g3, 256, 0, stream>>>(A2, woutb, b_out, out, nullptr, nullptr, nullptr);
}

// Round 5
// 267.619 us; speedup vs baseline: 1.0536x; 1.0536x over previous
//
#include <hip/hip_runtime.h>
#include <hip/hip_bf16.h>
#include <stdint.h>

#define B_    2
#define S_    4096
#define D_    768
#define H_    12
#define DH_   64
#define BH_   (B_*H_)
#define M_    (B_*S_)       // 8192
#define NQKV_ 2304
// 1/sqrt(64) * log2(e): Q pre-scaled so softmax runs in exp2 space
#define QSCALE_ 0.18033688011112042f

typedef unsigned short bf16u;
typedef short bf16x8 __attribute__((ext_vector_type(8)));
typedef float f32x4 __attribute__((ext_vector_type(4)));

__device__ __forceinline__ bf16u f2bf(float f) {
    unsigned u = __float_as_uint(f);
    u += 0x7FFFu + ((u >> 16) & 1u);   // round-to-nearest-even
    return (bf16u)(u >> 16);
}

__device__ __forceinline__ unsigned f2bf_pk(float a, float b) {
    return (unsigned)f2bf(a) | ((unsigned)f2bf(b) << 16);
}

__device__ __forceinline__ void gl_lds16(const void* g, void* l) {
    __builtin_amdgcn_global_load_lds(
        (const __attribute__((address_space(1))) unsigned*)g,
        (__attribute__((address_space(3))) unsigned*)l, 16, 0, 0);
}

// ---------------------------------------------------------------- convert
// three tensors in one launch (boundaries are multiples of 256 quads)
#define N1Q_ 1572864   // x      quads
#define N2Q_  442368   // W_qkv  quads
#define N3Q_  147456   // W_out  quads
__global__ __launch_bounds__(256) void convert3_kernel(
    const float* __restrict__ s1, const float* __restrict__ s2,
    const float* __restrict__ s3, bf16u* __restrict__ d1,
    bf16u* __restrict__ d2, bf16u* __restrict__ d3)
{
    int i = blockIdx.x * 256 + threadIdx.x;
    const float* s; bf16u* d; int j;
    if (i < N1Q_)              { s = s1; d = d1; j = i; }
    else if (i < N1Q_ + N2Q_)  { s = s2; d = d2; j = i - N1Q_; }
    else                       { s = s3; d = d3; j = i - N1Q_ - N2Q_; }
    float4 v = ((const float4*)s)[j];
    ushort4 o;
    o.x = f2bf(v.x); o.y = f2bf(v.y); o.z = f2bf(v.z); o.w = f2bf(v.w);
    ((ushort4*)d)[j] = o;
}

// ---------------------------------------------------------------- GEMM
// C[m][n] = sum_k A[m][k]*Bw[n][k] + bias[n].  K = 768 for both GEMMs.
// R5: double-buffered LDS (attn-proven 1-barrier/iter structure) — was
// single-buffered with 2 barriers per BK=32 step (48 full vmcnt(0) drains).
// LDS rows are 4 chunks of 16B; chunk-slot XOR-swizzled by (row&3).
// XCD-bijective block swizzle (T1) — grids are 1152 / 384, both %8==0.
// EPI==0: fp32 store to Cout.
// EPI==1: scatter to Qb(scaled)/Kb(bh,s,dh)/Vtb(bh,dh,s); V packed as uint2
//         (4 consecutive s per lane -> one 8B store instead of 4 ushort).
template<int EPI>
__global__ __launch_bounds__(256) void gemm_kernel(
    const bf16u* __restrict__ A, const bf16u* __restrict__ Bw,
    const float* __restrict__ bias, float* __restrict__ Cout,
    bf16u* __restrict__ Qb, bf16u* __restrict__ Kb, bf16u* __restrict__ Vtb)
{
    __shared__ bf16u As[2][128*32];
    __shared__ bf16u Bs[2][128*32];
    const int tid  = threadIdx.x;
    const int lane = tid & 63;
    const int wave = tid >> 6;
    const int wr = wave >> 1, wc = wave & 1;
    const int lr = lane & 15;
    const int quad = lane >> 4;

    const int nwg  = gridDim.x * gridDim.y;
    const int fblk = blockIdx.y * gridDim.x + blockIdx.x;
    const int vblk = (fblk & 7) * (nwg >> 3) + (fblk >> 3);
    const int m0 = (vblk / gridDim.x) * 128;
    const int n0 = (vblk % gridDim.x) * 128;

    f32x4 acc[4][4];
    #pragma unroll
    for (int i = 0; i < 4; i++)
        #pragma unroll
        for (int j = 0; j < 4; j++)
            acc[i][j] = (f32x4){0.f, 0.f, 0.f, 0.f};

    // stage k-tile k0 into buffer bf
    auto stage = [&](int k0, int bf) {
        #pragma unroll
        for (int r = 0; r < 2; r++) {
            int c = r * 256 + tid;              // 0..511 chunks of 16B
            int row = c >> 2;                   // 4 chunks per 64B row
            int col = ((c & 3) ^ (row & 3)) * 8; // XOR-swizzled source chunk
            gl_lds16(A  + (size_t)(m0 + row) * 768 + k0 + col,
                     (char*)&As[bf][0] + c * 16);
            gl_lds16(Bw + (size_t)(n0 + row) * 768 + k0 + col,
                     (char*)&Bs[bf][0] + c * 16);
        }
    };

    stage(0, 0);

    auto body = [&](int k0, int buf, bool do_stage) __attribute__((always_inline)) {
        __syncthreads();                   // tile k0 staged; prev compute done
        if (do_stage) stage(k0 + 32, buf ^ 1);
        bf16x8 af[4], bg[4];
        #pragma unroll
        for (int t = 0; t < 4; t++) {
            int ra = wr * 64 + t * 16 + lr;
            int rb = wc * 64 + t * 16 + lr;
            af[t] = *(const bf16x8*)(&As[buf][0] + ra * 32 + ((quad ^ (ra & 3)) * 8));
            bg[t] = *(const bf16x8*)(&Bs[buf][0] + rb * 32 + ((quad ^ (rb & 3)) * 8));
        }
        __builtin_amdgcn_s_setprio(1);
        #pragma unroll
        for (int i = 0; i < 4; i++)
            #pragma unroll
            for (int j = 0; j < 4; j++)
                acc[i][j] = __builtin_amdgcn_mfma_f32_16x16x32_bf16(
                    af[i], bg[j], acc[i][j], 0, 0, 0);
        __builtin_amdgcn_s_setprio(0);
    };

    // 24 k-steps; x2 unroll so buf is a literal; explicit 2-step tail
    #pragma unroll 1
    for (int k0 = 0; k0 < 768 - 64; k0 += 64) {
        body(k0,      0, true);
        body(k0 + 32, 1, true);
    }
    body(768 - 64, 0, true);
    body(768 - 32, 1, false);

    #pragma unroll
    for (int i = 0; i < 4; i++) {
        int mbase = m0 + wr * 64 + i * 16 + quad * 4;
        #pragma unroll
        for (int j = 0; j < 4; j++) {
            int n = n0 + wc * 64 + j * 16 + lr;
            float bv = bias[n];
            if (EPI == 0) {
                #pragma unroll
                for (int r = 0; r < 4; r++)
                    Cout[(size_t)(mbase + r) * 768 + n] = acc[i][j][r] + bv;
            } else {
                int t3  = n / 768;
                int rem = n - t3 * 768;
                int h   = rem >> 6;
                int dh  = rem & 63;
                int b   = mbase >> 12;      // all 4 r share b (mbase%4==0)
                int s0  = mbase & 4095;
                int bh  = b * H_ + h;
                if (t3 == 2) {
                    // V: 4 consecutive s for fixed dh -> one packed 8B store
                    uint2 pk;
                    pk.x = f2bf_pk(acc[i][j][0] + bv, acc[i][j][1] + bv);
                    pk.y = f2bf_pk(acc[i][j][2] + bv, acc[i][j][3] + bv);
                    *(uint2*)(Vtb + ((size_t)bh * DH_ + dh) * S_ + s0) = pk;
                } else if (t3 == 0) {
                    #pragma unroll
                    for (int r = 0; r < 4; r++)
                        Qb[((size_t)bh * S_ + s0 + r) * DH_ + dh] =
                            f2bf((acc[i][j][r] + bv) * QSCALE_);
                } else {
                    #pragma unroll
                    for (int r = 0; r < 4; r++)
                        Kb[((size_t)bh * S_ + s0 + r) * DH_ + dh] =
                            f2bf(acc[i][j][r] + bv);
                }
            }
        }
    }
}

// ---------------------------------------------------------------- attention
// R5: exact revert to the R3 structure (measured 109.7 µs, VGPR 40,
// bank-conflicts 0). R4's 4-wave variant traded 2x TLP for 2x per-wave
// LDS reuse and lost (114.5 µs) — kernel is latency-bound, needs waves.
//  * 8 waves x 512 threads; wave w owns q-rows [q0+16w, q0+16w+16).
//  * P in-register via T12 permlane network (no Ps LDS, no lgkm drain).
//  * XCD swizzle: 96 consecutive blocks (3 full bh panels) per XCD.
__global__ __launch_bounds__(512, 6) void attn_kernel(
    const bf16u* __restrict__ Qb, const bf16u* __restrict__ Kb,
    const bf16u* __restrict__ Vtb, bf16u* __restrict__ A2)
{
    __shared__ char Lds[32768];   // [K buf0 | K buf1 | V buf0 | V buf1], 8KB each
    const int tid  = threadIdx.x;
    const int lane = tid & 63;
    const int w    = tid >> 6;          // 0..7
    const int lr   = lane & 15;
    const int quad = lane >> 4;

    // XCD-bijective swizzle: 768 blocks, 96 per XCD (= 3 full bh panels)
    const int fblk = blockIdx.y * gridDim.x + blockIdx.x;
    const int vblk = (fblk & 7) * 96 + (fblk >> 3);
    const int q0   = (vblk & 31) * 128;
    const int bh   = vblk >> 5;

    const size_t kbase_g = (size_t)bh * S_ * DH_;
    const size_t vbase_g = (size_t)bh * DH_ * S_;

    // Q B-fragments: qrows q0+16w+lr, feats kstep*32+quad*8
    bf16x8 aq0, aq1;
    {
        const size_t qb = ((size_t)bh * S_ + q0 + w * 16 + lr) * DH_ + quad * 8;
        aq0 = *(const bf16x8*)(Qb + qb);
        aq1 = *(const bf16x8*)(Qb + qb + 32);
    }

    bf16x8 onesf;
    #pragma unroll
    for (int j = 0; j < 8; j++) onesf[j] = (short)0x3F80;  // bf16 1.0

    f32x4 o[4];          // C-layout: [qrow=quad*4+r2][dh=nt*16+lr]
    f32x4 l_acc = (f32x4){0.f, 0.f, 0.f, 0.f};
    #pragma unroll
    for (int t = 0; t < 4; t++) o[t] = (f32x4){0.f, 0.f, 0.f, 0.f};

    // Hoisted K/V LDS byte offsets (same swizzled geometry for K and V tiles).
    int kvaddr[4][2];
    #pragma unroll
    for (int nt = 0; nt < 4; nt++) {
        int rk = nt * 16 + lr;
        kvaddr[nt][0] = (rk * 64 + ((quad ^ (rk & 7)) * 8)) * 2;
        kvaddr[nt][1] = (rk * 64 + (((4 + quad) ^ (rk & 7)) * 8)) * 2;
    }

    // stage KV tile kv0 into buffer bf (512 threads -> 1 chunk each per matrix)
    auto stage = [&](int kv0, int bf) {
        int c = tid;                            // 0..511 chunks of 16B
        int row = c >> 3;
        int col = ((c & 7) ^ (row & 7)) * 8;    // XOR-swizzled source chunk
        gl_lds16(Kb  + kbase_g + (size_t)(kv0 + row) * DH_ + col,
                 Lds + bf * 8192 + c * 16);
        gl_lds16(Vtb + vbase_g + (size_t)row * S_ + kv0 + col,
                 Lds + 16384 + bf * 8192 + c * 16);
    };

    stage(0, 0);

    // one KV-tile step; buf/do_stage are compile-time constants per call site
    auto body = [&](int it, int buf, bool do_stage) __attribute__((always_inline)) {
        __syncthreads();                       // tile `it` staged; prev compute done
        if (do_stage) stage((it + 1) * 64, buf ^ 1);

        const char* Kbuf = Lds + buf * 8192;
        const char* Vbuf = Lds + 16384 + buf * 8192;

        // S^T = K @ Q^T  (exp2-scaled).  C[m=key_local][n=qrow_local]
        f32x4 sc[4];
        __builtin_amdgcn_s_setprio(1);
        #pragma unroll
        for (int nt = 0; nt < 4; nt++) {
            const bf16x8 bk0 = *(const bf16x8*)(Kbuf + kvaddr[nt][0]);
            const bf16x8 bk1 = *(const bf16x8*)(Kbuf + kvaddr[nt][1]);
            f32x4 s = (f32x4){0.f, 0.f, 0.f, 0.f};
            s = __builtin_amdgcn_mfma_f32_16x16x32_bf16(bk0, aq0, s, 0, 0, 0);
            s = __builtin_amdgcn_mfma_f32_16x16x32_bf16(bk1, aq1, s, 0, 0, 0);
            sc[nt] = s;
        }
        __builtin_amdgcn_s_setprio(0);

        // P = exp2(S): pack to bf16 pairs, all in-register
        unsigned W[4][2];
        #pragma unroll
        for (int nt = 0; nt < 4; nt++) {
            float p0 = __builtin_amdgcn_exp2f(sc[nt][0]);
            float p1 = __builtin_amdgcn_exp2f(sc[nt][1]);
            float p2 = __builtin_amdgcn_exp2f(sc[nt][2]);
            float p3 = __builtin_amdgcn_exp2f(sc[nt][3]);
            // pack high-16s (truncation; bias cancels in o/l ratio)
            W[nt][0] = __builtin_amdgcn_perm(__float_as_uint(p1),
                                             __float_as_uint(p0), 0x07060302u);
            W[nt][1] = __builtin_amdgcn_perm(__float_as_uint(p3),
                                             __float_as_uint(p2), 0x07060302u);
        }

        // permlane network: (W[2ks][b], W[2ks+1][b]) -> (a[ks][b], a[ks][2+b])
        bf16x8 ap[2];
        #pragma unroll
        for (int ks = 0; ks < 2; ks++) {
            union { unsigned u[4]; bf16x8 v; } Af;
            #pragma unroll
            for (int b = 0; b < 2; b++) {
                auto r1 = __builtin_amdgcn_permlane32_swap(
                    W[2 * ks][b], W[2 * ks + 1][b], false, false);
                auto r2 = __builtin_amdgcn_permlane16_swap(
                    r1[0], r1[1], false, false);
                Af.u[b]     = r2[0];
                Af.u[2 + b] = r2[1];
            }
            ap[ks] = Af.v;
        }

        // O += P @ V ; l += P @ 1
        __builtin_amdgcn_s_setprio(1);
        l_acc = __builtin_amdgcn_mfma_f32_16x16x32_bf16(ap[0], onesf, l_acc, 0, 0, 0);
        l_acc = __builtin_amdgcn_mfma_f32_16x16x32_bf16(ap[1], onesf, l_acc, 0, 0, 0);
        #pragma unroll
        for (int nt = 0; nt < 4; nt++) {
            const bf16x8 bv0 = *(const bf16x8*)(Vbuf + kvaddr[nt][0]);
            const bf16x8 bv1 = *(const bf16x8*)(Vbuf + kvaddr[nt][1]);
            o[nt] = __builtin_amdgcn_mfma_f32_16x16x32_bf16(ap[0], bv0, o[nt], 0, 0, 0);
            o[nt] = __builtin_amdgcn_mfma_f32_16x16x32_bf16(ap[1], bv1, o[nt], 0, 0, 0);
        }
        __builtin_amdgcn_s_setprio(0);
    };

    // unroll x2 so buf is a literal in each copy; explicit 2-tile tail
    #pragma unroll 1
    for (int it = 0; it < S_ / 64 - 2; it += 2) {
        body(it,     0, true);
        body(it + 1, 1, true);
    }
    body(S_ / 64 - 2, 0, true);
    body(S_ / 64 - 1, 1, false);

    const int b = bh / H_, h = bh % H_;
    float rl[4];
    #pragma unroll
    for (int r2 = 0; r2 < 4; r2++) rl[r2] = 1.0f / l_acc[r2];
    #pragma unroll
    for (int nt = 0; nt < 4; nt++)
        #pragma unroll
        for (int r2 = 0; r2 < 4; r2++) {
            int q = q0 + w * 16 + quad * 4 + r2;
            float v = o[nt][r2] * rl[r2];
            A2[((size_t)b * S_ + q) * D_ + h * DH_ + nt * 16 + lr] = f2bf(v);
        }
}

// ---------------------------------------------------------------- launch
extern "C" void kernel_launch(void* const* d_in, const int* in_sizes, int n_in,
                              void* d_out, int out_size, void* d_ws, size_t ws_size,
                              hipStream_t stream) {
    const float* x     = (const float*)d_in[0];
    const float* W_qkv = (const float*)d_in[1];
    const float* b_qkv = (const float*)d_in[2];
    const float* W_out = (const float*)d_in[3];
    const float* b_out = (const float*)d_in[4];
    float* out = (float*)d_out;
    char* ws = (char*)d_ws;

    // workspace layout (bytes, all 256-aligned)
    bf16u* xb    = (bf16u*)(ws + 0);          // 8192*768*2  = 12582912
    bf16u* wqkvb = (bf16u*)(ws + 12582912);   // 2304*768*2  =  3538944
    bf16u* woutb = (bf16u*)(ws + 16121856);   //  768*768*2  =  1179648
    bf16u* Qb    = (bf16u*)(ws + 17301504);   // 24*4096*64*2 = 12582912
    bf16u* Kb    = (bf16u*)(ws + 29884416);
    bf16u* Vtb   = (bf16u*)(ws + 42467328);
    bf16u* A2    = (bf16u*)(ws + 55050240);   // 8192*768*2

    convert3_kernel<<<(N1Q_ + N2Q_ + N3Q_) / 256, 256, 0, stream>>>(
        x, W_qkv, W_out, xb, wqkvb, woutb);

    dim3 g1(NQKV_/128, M_/128);   // 18 x 64 = 1152 blocks (%8==0)
    gemm_kernel<1><<<g1, 256, 0, stream>>>(xb, wqkvb, b_qkv, nullptr, Qb, Kb, Vtb);

    dim3 g2(S_/128, BH_);         // 32 x 24 = 768 blocks, 512 thr, 3/CU
    attn_kernel<<<g2, 512, 0, stream>>>(Qb, Kb, Vtb, A2);

    dim3 g3(D_/128, M_/128);      // 6 x 64 = 384 blocks (%8==0)
    gemm_kernel<0><<<g3, 256, 0, stream>>>(A2, woutb, b_out, out, nullptr, nullptr, nullptr);
}